// Round 1
// baseline (755.085 us; speedup 1.0000x reference)
//
#include <hip/hip_runtime.h>
#include <math.h>

#define BB 64
#define TT 1024
#define CC 64
#define HH 32
#define KNN 10

// ---------------- Kernel A: h = x@W1 + b1, sq[row] = |h_row|^2 ----------------
__global__ __launch_bounds__(256) void h_kernel(
    const float* __restrict__ x, const float* __restrict__ W1,
    const float* __restrict__ b1, float* __restrict__ h, float* __restrict__ sq)
{
    __shared__ float w1s[CC][HH];
    __shared__ float b1s[HH];
    int tid = threadIdx.x;
    for (int i = tid; i < CC * HH; i += 256) w1s[i >> 5][i & 31] = W1[i];
    if (tid < HH) b1s[tid] = b1[tid];
    __syncthreads();

    int row = blockIdx.x * 256 + tid;           // 0 .. B*T-1
    const float4* xr = (const float4*)(x + (size_t)row * CC);
    float acc[HH];
    #pragma unroll
    for (int j = 0; j < HH; ++j) acc[j] = b1s[j];
    #pragma unroll
    for (int c4 = 0; c4 < CC / 4; ++c4) {
        float4 xv = xr[c4];
        #pragma unroll
        for (int j = 0; j < HH; ++j) {
            acc[j] = fmaf(xv.x, w1s[c4 * 4 + 0][j], acc[j]);
            acc[j] = fmaf(xv.y, w1s[c4 * 4 + 1][j], acc[j]);
            acc[j] = fmaf(xv.z, w1s[c4 * 4 + 2][j], acc[j]);
            acc[j] = fmaf(xv.w, w1s[c4 * 4 + 3][j], acc[j]);
        }
    }
    float s = 0.f;
    #pragma unroll
    for (int j = 0; j < HH; ++j) s = fmaf(acc[j], acc[j], s);
    float* hr = h + (size_t)row * HH;
    #pragma unroll
    for (int q = 0; q < HH / 4; ++q) {
        float4 v = { acc[4*q], acc[4*q+1], acc[4*q+2], acc[4*q+3] };
        ((float4*)hr)[q] = v;
    }
    sq[row] = s;
}

// ------------- Kernel B: kNN + laplace smooth + tanh + W2 GEMM ---------------
// grid = B * (T/64) blocks, 256 threads (4 waves).
// Each wave: 64 rows (1 per lane). 4 waves split the s-range 4-ways.
__global__ __launch_bounds__(256) void lap_kernel(
    const float* __restrict__ h, const float* __restrict__ sq,
    const float* __restrict__ W2, const float* __restrict__ b2,
    float* __restrict__ out)
{
    __shared__ float s_key[4][64][KNN];
    __shared__ int   s_idx[4][64][KNN];
    __shared__ float a_lds[64][HH + 1];
    __shared__ float w2s[HH][HH];
    __shared__ float b2s[HH];

    int tid  = threadIdx.x;
    int lane = tid & 63;
    int wid  = __builtin_amdgcn_readfirstlane(tid >> 6);

    int bb = blockIdx.x >> 4;            // batch index (16 row-blocks / batch)
    int rb = (blockIdx.x & 15) << 6;     // row base within batch
    int row = rb + lane;

    for (int i = tid; i < HH * HH; i += 256) w2s[i >> 5][i & 31] = W2[i];
    if (tid < HH) b2s[tid] = b2[tid];

    const float* hb  = h  + (size_t)bb * TT * HH;
    const float* sqb = sq + (size_t)bb * TT;

    // own row into registers
    float ht[HH];
    {
        const float4* hrp = (const float4*)(hb + (size_t)row * HH);
        #pragma unroll
        for (int q = 0; q < HH / 4; ++q) {
            float4 v = hrp[q];
            ht[q*4+0] = v.x; ht[q*4+1] = v.y; ht[q*4+2] = v.z; ht[q*4+3] = v.w;
        }
    }

    // per-thread top-10 over this wave's s-chunk
    float bd[KNN]; int bi[KNN];
    #pragma unroll
    for (int j = 0; j < KNN; ++j) { bd[j] = 3.0e38f; bi[j] = -1; }

    int s0 = wid * (TT / 4);
    for (int i = 0; i < TT / 4; ++i) {
        int s = s0 + i;                              // wave-uniform
        const float4* hsp = (const float4*)(hb + (size_t)s * HH);
        float a0 = 0.f, a1 = 0.f, a2 = 0.f, a3 = 0.f;
        #pragma unroll
        for (int q = 0; q < HH / 4; ++q) {
            float4 v = hsp[q];
            a0 = fmaf(ht[q*4+0], v.x, a0);
            a1 = fmaf(ht[q*4+1], v.y, a1);
            a2 = fmaf(ht[q*4+2], v.z, a2);
            a3 = fmaf(ht[q*4+3], v.w, a3);
        }
        float dot = (a0 + a1) + (a2 + a3);
        float key = fmaf(-2.f, dot, sqb[s]);          // d2 - sq_t (monotone)
        key = (s == row) ? 3.0e38f : key;             // exclude self
        if (key < bd[KNN - 1]) {                      // sorted branchless insert
            #pragma unroll
            for (int j = KNN - 1; j >= 1; --j) {
                bool wr = key < bd[j];
                bool sh = key < bd[j - 1];
                float nv = sh ? bd[j - 1] : key;
                int   ni = sh ? bi[j - 1] : s;
                bd[j] = wr ? nv : bd[j];
                bi[j] = wr ? ni : bi[j];
            }
            bool w0 = key < bd[0];
            bd[0] = w0 ? key : bd[0];
            bi[0] = w0 ? s : bi[0];
        }
    }

    #pragma unroll
    for (int j = 0; j < KNN; ++j) {
        s_key[wid][lane][j] = bd[j];
        s_idx[wid][lane][j] = bi[j];
    }
    __syncthreads();

    if (wid == 0) {
        // merge the 4 sorted lists (chunk order == ascending s => stable ties)
        int p0 = 0, p1 = 0, p2 = 0, p3 = 0;
        float h0 = s_key[0][lane][0], h1 = s_key[1][lane][0];
        float h2 = s_key[2][lane][0], h3 = s_key[3][lane][0];
        int idxs[KNN];
        #pragma unroll
        for (int j = 0; j < KNN; ++j) {
            int c = 0; float m = h0;
            if (h1 < m) { m = h1; c = 1; }
            if (h2 < m) { m = h2; c = 2; }
            if (h3 < m) { m = h3; c = 3; }
            if (c == 0)      { idxs[j] = s_idx[0][lane][p0]; ++p0; h0 = (p0 < KNN) ? s_key[0][lane][p0] : 3.0e38f; }
            else if (c == 1) { idxs[j] = s_idx[1][lane][p1]; ++p1; h1 = (p1 < KNN) ? s_key[1][lane][p1] : 3.0e38f; }
            else if (c == 2) { idxs[j] = s_idx[2][lane][p2]; ++p2; h2 = (p2 < KNN) ? s_key[2][lane][p2] : 3.0e38f; }
            else             { idxs[j] = s_idx[3][lane][p3]; ++p3; h3 = (p3 < KNN) ? s_key[3][lane][p3] : 3.0e38f; }
        }

        // exact weights + smooth (matches reference's gathered-diff path)
        float sm[HH];
        #pragma unroll
        for (int j = 0; j < HH; ++j) sm[j] = 0.f;
        float wsum = 0.f;
        #pragma unroll
        for (int k = 0; k < KNN; ++k) {
            const float4* np_ = (const float4*)(hb + (size_t)idxs[k] * HH);
            float nb[HH];
            #pragma unroll
            for (int q = 0; q < HH / 4; ++q) {
                float4 v = np_[q];
                nb[q*4+0] = v.x; nb[q*4+1] = v.y; nb[q*4+2] = v.z; nb[q*4+3] = v.w;
            }
            float d2 = 0.f;
            #pragma unroll
            for (int j = 0; j < HH; ++j) {
                float df = nb[j] - ht[j];
                d2 = fmaf(df, df, d2);
            }
            float wk = expf(-0.5f * d2);
            wsum += wk;
            #pragma unroll
            for (int j = 0; j < HH; ++j) sm[j] = fmaf(wk, nb[j], sm[j]);
        }
        float inv = 1.0f / (wsum + 1e-8f);
        #pragma unroll
        for (int j = 0; j < HH; ++j) {
            float lap = ht[j] - sm[j] * inv;
            a_lds[lane][j] = tanhf(lap);
        }
    }
    __syncthreads();

    // out = a @ W2 + b2 ; thread -> (row r, 8 consecutive output dims)
    int r   = tid >> 2;
    int c0  = (tid & 3) << 3;
    float o[8];
    #pragma unroll
    for (int u = 0; u < 8; ++u) o[u] = b2s[c0 + u];
    #pragma unroll
    for (int j = 0; j < HH; ++j) {
        float av = a_lds[r][j];
        #pragma unroll
        for (int u = 0; u < 8; ++u) o[u] = fmaf(av, w2s[j][c0 + u], o[u]);
    }
    float* op = out + ((size_t)bb * TT + rb + r) * HH + c0;
    float4 o1 = { o[0], o[1], o[2], o[3] };
    float4 o2 = { o[4], o[5], o[6], o[7] };
    ((float4*)op)[0] = o1;
    ((float4*)op)[1] = o2;
}

extern "C" void kernel_launch(void* const* d_in, const int* in_sizes, int n_in,
                              void* d_out, int out_size, void* d_ws, size_t ws_size,
                              hipStream_t stream) {
    const float* x  = (const float*)d_in[0];
    const float* W1 = (const float*)d_in[1];
    const float* b1 = (const float*)d_in[2];
    const float* W2 = (const float*)d_in[3];
    const float* b2 = (const float*)d_in[4];
    float* outp = (float*)d_out;

    // workspace layout: h (B*T*H floats) | sq (B*T floats)  ~= 8.65 MB
    float* h  = (float*)d_ws;
    float* sq = h + (size_t)BB * TT * HH;

    h_kernel<<<(BB * TT) / 256, 256, 0, stream>>>(x, W1, b1, h, sq);
    lap_kernel<<<BB * (TT / 64), 256, 0, stream>>>(h, sq, W2, b2, outp);
}

// Round 2
// 209.622 us; speedup vs baseline: 3.6021x; 3.6021x over previous
//
#include <hip/hip_runtime.h>
#include <math.h>

#define BB 64
#define TT 1024
#define CC 64
#define HH 32
#define KNN 10
#define BIGF 3.0e38f

// ---------------- Kernel A: h = x@W1 + b1, sq[row] = |h_row|^2 ----------------
__global__ __launch_bounds__(256) void h_kernel(
    const float* __restrict__ x, const float* __restrict__ W1,
    const float* __restrict__ b1, float* __restrict__ h, float* __restrict__ sq)
{
    __shared__ float w1s[CC][HH];
    __shared__ float b1s[HH];
    int tid = threadIdx.x;
    for (int i = tid; i < CC * HH; i += 256) w1s[i >> 5][i & 31] = W1[i];
    if (tid < HH) b1s[tid] = b1[tid];
    __syncthreads();

    int row = blockIdx.x * 256 + tid;           // 0 .. B*T-1
    const float4* xr = (const float4*)(x + (size_t)row * CC);
    float acc[HH];
    #pragma unroll
    for (int j = 0; j < HH; ++j) acc[j] = b1s[j];
    #pragma unroll
    for (int c4 = 0; c4 < CC / 4; ++c4) {
        float4 xv = xr[c4];
        #pragma unroll
        for (int j = 0; j < HH; ++j) {
            acc[j] = fmaf(xv.x, w1s[c4 * 4 + 0][j], acc[j]);
            acc[j] = fmaf(xv.y, w1s[c4 * 4 + 1][j], acc[j]);
            acc[j] = fmaf(xv.z, w1s[c4 * 4 + 2][j], acc[j]);
            acc[j] = fmaf(xv.w, w1s[c4 * 4 + 3][j], acc[j]);
        }
    }
    float s = 0.f;
    #pragma unroll
    for (int j = 0; j < HH; ++j) s = fmaf(acc[j], acc[j], s);
    float* hr = h + (size_t)row * HH;
    #pragma unroll
    for (int q = 0; q < HH / 4; ++q) {
        float4 v = { acc[4*q], acc[4*q+1], acc[4*q+2], acc[4*q+3] };
        ((float4*)hr)[q] = v;
    }
    sq[row] = s;
}

// ------------- Kernel B: kNN + laplace smooth + tanh + W2 GEMM ---------------
// grid = B * (T/64) blocks, 256 threads (4 waves).
// Each wave: 64 rows (1 per lane). 4 waves split the s-range 4-ways.
// __launch_bounds__(256,4): force <=128 VGPR so 4 blocks/CU co-reside
// (LDS 33KB allows 4); hot loop needs ~80 live regs, spills hit epilogue only.
__global__ __launch_bounds__(256, 4) void lap_kernel(
    const float* __restrict__ h, const float* __restrict__ sq,
    const float* __restrict__ W2, const float* __restrict__ b2,
    float* __restrict__ out)
{
    __shared__ float s_key[4][64][KNN];
    __shared__ int   s_idx[4][64][KNN];
    __shared__ float a_lds[64][HH + 1];
    __shared__ float w2s[HH][HH];
    __shared__ float b2s[HH];

    int tid  = threadIdx.x;
    int lane = tid & 63;
    int wid  = __builtin_amdgcn_readfirstlane(tid >> 6);

    int bb = blockIdx.x >> 4;            // batch index (16 row-blocks / batch)
    int rb = (blockIdx.x & 15) << 6;     // row base within batch
    int row = rb + lane;

    for (int i = tid; i < HH * HH; i += 256) w2s[i >> 5][i & 31] = W2[i];
    if (tid < HH) b2s[tid] = b2[tid];

    const float* hb  = h  + (size_t)bb * TT * HH;
    const float* sqb = sq + (size_t)bb * TT;

    // own row into registers
    float ht[HH];
    {
        const float4* hrp = (const float4*)(hb + (size_t)row * HH);
        #pragma unroll
        for (int q = 0; q < HH / 4; ++q) {
            float4 v = hrp[q];
            ht[q*4+0] = v.x; ht[q*4+1] = v.y; ht[q*4+2] = v.z; ht[q*4+3] = v.w;
        }
    }

    // per-thread top-10 over this wave's s-chunk (branchless, prefetched)
    float bd[KNN]; int bi[KNN];
    #pragma unroll
    for (int j = 0; j < KNN; ++j) { bd[j] = BIGF; bi[j] = -1; }

    int s0 = wid * (TT / 4);
    // prefetch iteration 0
    float4 p0, p1; float psq;
    {
        const float4* hsp = (const float4*)(hb + (size_t)s0 * HH);
        p0 = hsp[0]; p1 = hsp[1]; psq = sqb[s0];
    }
    #pragma unroll 4
    for (int i = 0; i < TT / 4; ++i) {
        int s  = s0 + i;                             // wave-uniform
        int sn = s0 + ((i + 1) & (TT / 4 - 1));      // wrap: harmless reload
        const float4* hnp = (const float4*)(hb + (size_t)sn * HH);
        float4 n0 = hnp[0];
        float4 n1 = hnp[1];
        float  nsq = sqb[sn];

        float a0 = 0.f, a1 = 0.f, a2 = 0.f, a3 = 0.f;
        a0 = fmaf(ht[0], p0.x, a0); a1 = fmaf(ht[1], p0.y, a1);
        a2 = fmaf(ht[2], p0.z, a2); a3 = fmaf(ht[3], p0.w, a3);
        a0 = fmaf(ht[4], p1.x, a0); a1 = fmaf(ht[5], p1.y, a1);
        a2 = fmaf(ht[6], p1.z, a2); a3 = fmaf(ht[7], p1.w, a3);
        const float4* hsp = (const float4*)(hb + (size_t)s * HH);
        #pragma unroll
        for (int q = 2; q < HH / 4; ++q) {
            float4 v = hsp[q];
            a0 = fmaf(ht[q*4+0], v.x, a0);
            a1 = fmaf(ht[q*4+1], v.y, a1);
            a2 = fmaf(ht[q*4+2], v.z, a2);
            a3 = fmaf(ht[q*4+3], v.w, a3);
        }
        float dot = (a0 + a1) + (a2 + a3);
        float key = fmaf(-2.f, dot, psq);            // d2 - sq_t (monotone)
        key = (s == row) ? BIGF : key;               // exclude self

        // branchless sorted insert (taken ~every iter anyway at 256 cand/wave)
        #pragma unroll
        for (int j = KNN - 1; j >= 1; --j) {
            bool wr = key < bd[j];
            bool sh = key < bd[j - 1];
            bd[j] = wr ? (sh ? bd[j - 1] : key) : bd[j];
            bi[j] = wr ? (sh ? bi[j - 1] : s ) : bi[j];
        }
        bool w0 = key < bd[0];
        bd[0] = w0 ? key : bd[0];
        bi[0] = w0 ? s : bi[0];

        p0 = n0; p1 = n1; psq = nsq;
    }

    #pragma unroll
    for (int j = 0; j < KNN; ++j) {
        s_key[wid][lane][j] = bd[j];
        s_idx[wid][lane][j] = bi[j];
    }
    __syncthreads();

    if (wid == 0) {
        // merge the 4 sorted lists (chunk order == ascending s => stable ties)
        int p0_ = 0, p1_ = 0, p2_ = 0, p3_ = 0;
        float h0 = s_key[0][lane][0], h1 = s_key[1][lane][0];
        float h2 = s_key[2][lane][0], h3 = s_key[3][lane][0];
        int idxs[KNN];
        #pragma unroll
        for (int j = 0; j < KNN; ++j) {
            int c = 0; float m = h0;
            if (h1 < m) { m = h1; c = 1; }
            if (h2 < m) { m = h2; c = 2; }
            if (h3 < m) { m = h3; c = 3; }
            if (c == 0)      { idxs[j] = s_idx[0][lane][p0_]; ++p0_; h0 = (p0_ < KNN) ? s_key[0][lane][p0_] : BIGF; }
            else if (c == 1) { idxs[j] = s_idx[1][lane][p1_]; ++p1_; h1 = (p1_ < KNN) ? s_key[1][lane][p1_] : BIGF; }
            else if (c == 2) { idxs[j] = s_idx[2][lane][p2_]; ++p2_; h2 = (p2_ < KNN) ? s_key[2][lane][p2_] : BIGF; }
            else             { idxs[j] = s_idx[3][lane][p3_]; ++p3_; h3 = (p3_ < KNN) ? s_key[3][lane][p3_] : BIGF; }
        }

        // exact weights + smooth (matches reference's gathered-diff path)
        float sm[HH];
        #pragma unroll
        for (int j = 0; j < HH; ++j) sm[j] = 0.f;
        float wsum = 0.f;
        #pragma unroll 2
        for (int k = 0; k < KNN; ++k) {
            const float4* np_ = (const float4*)(hb + (size_t)idxs[k] * HH);
            float nb[HH];
            #pragma unroll
            for (int q = 0; q < HH / 4; ++q) {
                float4 v = np_[q];
                nb[q*4+0] = v.x; nb[q*4+1] = v.y; nb[q*4+2] = v.z; nb[q*4+3] = v.w;
            }
            float d2 = 0.f;
            #pragma unroll
            for (int j = 0; j < HH; ++j) {
                float df = nb[j] - ht[j];
                d2 = fmaf(df, df, d2);
            }
            float wk = expf(-0.5f * d2);
            wsum += wk;
            #pragma unroll
            for (int j = 0; j < HH; ++j) sm[j] = fmaf(wk, nb[j], sm[j]);
        }
        float inv = 1.0f / (wsum + 1e-8f);
        #pragma unroll
        for (int j = 0; j < HH; ++j) {
            float lap = ht[j] - sm[j] * inv;
            a_lds[lane][j] = tanhf(lap);
        }
    }
    __syncthreads();

    // out = a @ W2 + b2 ; thread -> (row r, 8 consecutive output dims)
    int r   = tid >> 2;
    int c0  = (tid & 3) << 3;
    float o[8];
    #pragma unroll
    for (int u = 0; u < 8; ++u) o[u] = b2s[c0 + u];
    #pragma unroll
    for (int j = 0; j < HH; ++j) {
        float av = a_lds[r][j];
        #pragma unroll
        for (int u = 0; u < 8; ++u) o[u] = fmaf(av, w2s[j][c0 + u], o[u]);
    }
    float* op = out + ((size_t)bb * TT + rb + r) * HH + c0;
    float4 o1 = { o[0], o[1], o[2], o[3] };
    float4 o2 = { o[4], o[5], o[6], o[7] };
    ((float4*)op)[0] = o1;
    ((float4*)op)[1] = o2;
}

extern "C" void kernel_launch(void* const* d_in, const int* in_sizes, int n_in,
                              void* d_out, int out_size, void* d_ws, size_t ws_size,
                              hipStream_t stream) {
    const float* x  = (const float*)d_in[0];
    const float* W1 = (const float*)d_in[1];
    const float* b1 = (const float*)d_in[2];
    const float* W2 = (const float*)d_in[3];
    const float* b2 = (const float*)d_in[4];
    float* outp = (float*)d_out;

    // workspace layout: h (B*T*H floats) | sq (B*T floats)  ~= 8.65 MB
    float* h  = (float*)d_ws;
    float* sq = h + (size_t)BB * TT * HH;

    h_kernel<<<(BB * TT) / 256, 256, 0, stream>>>(x, W1, b1, h, sq);
    lap_kernel<<<BB * (TT / 64), 256, 0, stream>>>(h, sq, W2, b2, outp);
}